// Round 11
// baseline (341.303 us; speedup 1.0000x reference)
//
#include <hip/hip_runtime.h>

#define NROWS 8192
#define DDIM 256
#define MARGIN_F 0.2f
#define NSLOT 128             // partial slots per row = 64-row tile groups
#define NTT 128               // tile groups (8192/64)

typedef _Float16 half8 __attribute__((ext_vector_type(8)));
typedef float f32x4 __attribute__((ext_vector_type(4)));
typedef int i32x4 __attribute__((ext_vector_type(4)));

// ---------------- kernel 1: split fp32 -> hi/lo fp16 in 16x16x32-MFMA-tiled layout + sq ------
// Chunk (rg=16-row group, kb=K32 tile) = 1024B at ((rg*8+kb)*512 halves):
// [g 0..3][r 0..15][8 halves]; lane l maps to byte offset l*16 (r=l&15, g=l>>4).
__global__ __launch_bounds__(256)
void prep_kernel(const float* __restrict__ E, _Float16* __restrict__ Eh,
                 _Float16* __restrict__ El, float* __restrict__ sq) {
  const int t = threadIdx.x;
  const int r = t >> 4;        // row within 16-row group
  const int cs = t & 15;       // 16-col segment
  const int rg = blockIdx.x;
  const int row = rg * 16 + r;
  const float* src = &E[row * DDIM + cs * 16];
  float s = 0.f;
  half8 H[2], L[2];
#pragma unroll
  for (int h = 0; h < 2; ++h) {
    const float4 f0 = *(const float4*)(src + h * 8);
    const float4 f1 = *(const float4*)(src + h * 8 + 4);
    const float v[8] = {f0.x, f0.y, f0.z, f0.w, f1.x, f1.y, f1.z, f1.w};
#pragma unroll
    for (int e = 0; e < 8; ++e) {
      s = fmaf(v[e], v[e], s);
      const _Float16 hi = (_Float16)v[e];
      H[h][e] = hi;
      L[h][e] = (_Float16)(v[e] - (float)hi);
    }
  }
  const int kb = cs >> 1;
  const int g0 = (cs & 1) * 2;
  const int base = (rg * 8 + kb) * 512;
  *(half8*)&Eh[base + g0 * 128 + r * 8] = H[0];
  *(half8*)&Eh[base + (g0 + 1) * 128 + r * 8] = H[1];
  *(half8*)&El[base + g0 * 128 + r * 8] = L[0];
  *(half8*)&El[base + (g0 + 1) * 128 + r * 8] = L[1];
#pragma unroll
  for (int o = 8; o > 0; o >>= 1) s += __shfl_down(s, o, 16);
  if (cs == 0) sq[row] = s;
}

// ---------------- kernel 2: barrier-free per-wave 64x64 split-f16 MFMA dist + mining --------
// 16384 blocks x 64 thr. Logical tile g: band(8 by-rows) x bx-major, XCD-chunked.
// by > bx -> exit (triangular). Fragments loaded DIRECTLY global->reg (no LDS, no barriers).
// mfma(A=Ej frag, B=Ei frag): D[j][i], i = lane&15 (+16fi), j = (lane>>4)*4+reg (+16jf).
__global__ __launch_bounds__(64)
void mine_kernel(const _Float16* __restrict__ Eh, const _Float16* __restrict__ El,
                 const int* __restrict__ T, const float* __restrict__ sq,
                 float* __restrict__ pv, int* __restrict__ pi,
                 float* __restrict__ nv, int* __restrict__ ni) {
  // XCD chunking: hw block d -> logical g so each XCD owns a contiguous 2048-range
  const int d = blockIdx.x;
  const int g = (d & 7) * 2048 + (d >> 3);
  const int band = g >> 10;            // 16 bands of (8 by) x (128 bx)
  const int bx = (g >> 3) & 127;
  const int by = band * 8 + (g & 7);
  if (by > bx) return;                 // strict lower triangle: skip
  const bool offdiag = (bx != by);
  const int ib = by * 64, jb0 = bx * 64;

  const int lane = threadIdx.x;
  const int l15 = lane & 15, grp = lane >> 4;

  // fragment base offsets (halves): chunk rg = tile*4 + f, addr = rg*4096 + kb*512 + lane*8
  int offB[4], offA[4];
#pragma unroll
  for (int f = 0; f < 4; ++f) {
    offB[f] = (by * 4 + f) * 4096 + lane * 8;   // i-side (B operand)
    offA[f] = (bx * 4 + f) * 4096 + lane * 8;   // j-side (A operand)
  }

  f32x4 acc[4][4];
#pragma unroll
  for (int jf = 0; jf < 4; ++jf)
#pragma unroll
    for (int fi = 0; fi < 4; ++fi) acc[jf][fi] = (f32x4){0.f, 0.f, 0.f, 0.f};

#define LOADSET(AH, AL, BH, BL, KB) do { const int kk_ = (KB) * 512;            \
    _Pragma("unroll")                                                           \
    for (int f = 0; f < 4; ++f) {                                               \
      AH[f] = *(const half8*)&Eh[offA[f] + kk_];                                \
      AL[f] = *(const half8*)&El[offA[f] + kk_];                                \
      BH[f] = *(const half8*)&Eh[offB[f] + kk_];                                \
      BL[f] = *(const half8*)&El[offB[f] + kk_];                                \
    } } while (0)

#define MM(AH, AL, BH, BL) do {                                                 \
    _Pragma("unroll")                                                           \
    for (int fi = 0; fi < 4; ++fi)                                              \
      _Pragma("unroll")                                                         \
      for (int jf = 0; jf < 4; ++jf)                                            \
        acc[jf][fi] = __builtin_amdgcn_mfma_f32_16x16x32_f16(AH[jf], BH[fi], acc[jf][fi], 0, 0, 0); \
    _Pragma("unroll")                                                           \
    for (int fi = 0; fi < 4; ++fi)                                              \
      _Pragma("unroll")                                                         \
      for (int jf = 0; jf < 4; ++jf)                                            \
        acc[jf][fi] = __builtin_amdgcn_mfma_f32_16x16x32_f16(AL[jf], BH[fi], acc[jf][fi], 0, 0, 0); \
    _Pragma("unroll")                                                           \
    for (int fi = 0; fi < 4; ++fi)                                              \
      _Pragma("unroll")                                                         \
      for (int jf = 0; jf < 4; ++jf)                                            \
        acc[jf][fi] = __builtin_amdgcn_mfma_f32_16x16x32_f16(AH[jf], BL[fi], acc[jf][fi], 0, 0, 0); \
    } while (0)

  half8 AH0[4], AL0[4], BH0[4], BL0[4];
  half8 AH1[4], AL1[4], BH1[4], BL1[4];
  LOADSET(AH0, AL0, BH0, BL0, 0);
#pragma unroll
  for (int it = 0; it < 4; ++it) {
    LOADSET(AH1, AL1, BH1, BL1, 2 * it + 1);
    MM(AH0, AL0, BH0, BL0);
    if (it < 3) LOADSET(AH0, AL0, BH0, BL0, 2 * it + 2);
    MM(AH1, AL1, BH1, BL1);
  }
#undef LOADSET
#undef MM

  // ---- mining (all scans ascending + idx tie-breaks -> reference first-index semantics) ----
  float sqi[4]; int ti[4];
#pragma unroll
  for (int fi = 0; fi < 4; ++fi) {
    sqi[fi] = sq[ib + fi * 16 + l15];
    ti[fi] = T[ib + fi * 16 + l15];
  }
  float bpv[4], bnv[4]; int bpi[4], bni[4];
#pragma unroll
  for (int fi = 0; fi < 4; ++fi) { bpv[fi] = -3e38f; bnv[fi] = 3e38f; bpi[fi] = 0; bni[fi] = 0; }

#pragma unroll
  for (int jf = 0; jf < 4; ++jf) {
    const int jb = jb0 + jf * 16 + grp * 4;
    const f32x4 sqj = *(const f32x4*)&sq[jb];
    const i32x4 tj = *(const i32x4*)&T[jb];
    // row-side: anchor i lane-local, candidates j (ascending within lane)
#pragma unroll
    for (int fi = 0; fi < 4; ++fi) {
#pragma unroll
      for (int r = 0; r < 4; ++r) {
        const float dst = fmaf(-2.f, acc[jf][fi][r], sqi[fi] + sqj[r]);
        const int jidx = jb + r;
        if (ti[fi] == tj[r]) {
          if (dst > bpv[fi]) { bpv[fi] = dst; bpi[fi] = jidx; }
        } else {
          if (dst < bnv[fi]) { bnv[fi] = dst; bni[fi] = jidx; }
        }
      }
    }
    // transposed: anchor j, candidates i (in-lane fi scan ascending, then l15 butterfly)
    if (offdiag) {
#pragma unroll
      for (int r = 0; r < 4; ++r) {
        float tpv = -3e38f, tnv = 3e38f; int tpi = 0, tni = 0;
#pragma unroll
        for (int fi = 0; fi < 4; ++fi) {
          const float dst = fmaf(-2.f, acc[jf][fi][r], sqi[fi] + sqj[r]);
          const int ii = ib + fi * 16 + l15;
          if (ti[fi] == tj[r]) {
            if (dst > tpv) { tpv = dst; tpi = ii; }
          } else {
            if (dst < tnv) { tnv = dst; tni = ii; }
          }
        }
#pragma unroll
        for (int m = 1; m <= 8; m <<= 1) {   // butterfly within the 16-lane group
          const float ov = __shfl_xor(tpv, m, 64);
          const int oi = __shfl_xor(tpi, m, 64);
          if (ov > tpv || (ov == tpv && oi < tpi)) { tpv = ov; tpi = oi; }
          const float on = __shfl_xor(tnv, m, 64);
          const int oni = __shfl_xor(tni, m, 64);
          if (on < tnv || (on == tnv && oni < tni)) { tnv = on; tni = oni; }
        }
        if (l15 == jf * 4 + r) {             // one writer per (jf,r) per group
          const int j = jb0 + jf * 16 + grp * 4 + r;
          const int o = j * NSLOT + by;
          pv[o] = tpv; pi[o] = tpi; nv[o] = tnv; ni[o] = tni;
        }
      }
    }
  }

  // row-side: combine the 4 lane-groups (disjoint j quarters), idx tie-break
#pragma unroll
  for (int fi = 0; fi < 4; ++fi) {
#pragma unroll
    for (int off = 16; off <= 32; off <<= 1) {
      const float ov = __shfl_xor(bpv[fi], off, 64);
      const int oi = __shfl_xor(bpi[fi], off, 64);
      if (ov > bpv[fi] || (ov == bpv[fi] && oi < bpi[fi])) { bpv[fi] = ov; bpi[fi] = oi; }
      const float on = __shfl_xor(bnv[fi], off, 64);
      const int oni = __shfl_xor(bni[fi], off, 64);
      if (on < bnv[fi] || (on == bnv[fi] && oni < bni[fi])) { bnv[fi] = on; bni[fi] = oni; }
    }
  }
#pragma unroll
  for (int fi = 0; fi < 4; ++fi) {
    if (grp == fi) {                         // lane == fi*16 + l15 writes row ib+lane
      const int o = (ib + lane) * NSLOT + bx;
      pv[o] = bpv[fi]; pi[o] = bpi[fi]; nv[o] = bnv[fi]; ni[o] = bni[fi];
    }
  }
}

// ---------------- kernel 3: combine 128 slots, exact ap/an, losses, triplets ----------------
__global__ __launch_bounds__(256)
void finish_kernel(const float* __restrict__ E,
                   const float* __restrict__ pv, const int* __restrict__ pi,
                   const float* __restrict__ nv, const int* __restrict__ ni,
                   float* __restrict__ out, float* __restrict__ bl) {
  const int w = threadIdx.x >> 6, lane = threadIdx.x & 63;
  const int row = blockIdx.x * 4 + w;
  float Pv = -3e38f, Nv = 3e38f; int Pi = 0, Ni = 0;
  for (int s = 0; s < NSLOT; ++s) {
    const float p = pv[row * NSLOT + s]; const int px = pi[row * NSLOT + s];
    if (p > Pv || (p == Pv && px < Pi)) { Pv = p; Pi = px; }
    const float n = nv[row * NSLOT + s]; const int nx = ni[row * NSLOT + s];
    if (n < Nv || (n == Nv && nx < Ni)) { Nv = n; Ni = nx; }
  }
  const float4 a = *(const float4*)&E[row * DDIM + lane * 4];
  const float4 p4 = *(const float4*)&E[Pi * DDIM + lane * 4];
  const float4 n4 = *(const float4*)&E[Ni * DDIM + lane * 4];
  float ap = (a.x - p4.x) * (a.x - p4.x) + (a.y - p4.y) * (a.y - p4.y)
           + (a.z - p4.z) * (a.z - p4.z) + (a.w - p4.w) * (a.w - p4.w);
  float an = (a.x - n4.x) * (a.x - n4.x) + (a.y - n4.y) * (a.y - n4.y)
           + (a.z - n4.z) * (a.z - n4.z) + (a.w - n4.w) * (a.w - n4.w);
#pragma unroll
  for (int o = 32; o > 0; o >>= 1) {
    ap += __shfl_down(ap, o, 64);
    an += __shfl_down(an, o, 64);
  }
  __shared__ float ls[4];
  if (lane == 0) {
    out[1 + row * 3 + 0] = (float)row;
    out[1 + row * 3 + 1] = (float)Pi;
    out[1 + row * 3 + 2] = (float)Ni;
    ls[w] = fmaxf(ap - an + MARGIN_F, 0.f);
  }
  __syncthreads();
  if (threadIdx.x == 0) bl[blockIdx.x] = (ls[0] + ls[1]) + (ls[2] + ls[3]);
}

// ---------------- kernel 4: deterministic mean ----------------
__global__ __launch_bounds__(256)
void sum_kernel(const float* __restrict__ bl, float* __restrict__ out) {
  __shared__ float s[256];
  float t = 0.f;
#pragma unroll
  for (int r = 0; r < (NROWS / 4) / 256; ++r) t += bl[threadIdx.x + r * 256];
  s[threadIdx.x] = t;
  __syncthreads();
  for (int o = 128; o > 0; o >>= 1) {
    if (threadIdx.x < o) s[threadIdx.x] += s[threadIdx.x + o];
    __syncthreads();
  }
  if (threadIdx.x == 0) out[0] = s[0] * (1.f / NROWS);
}

extern "C" void kernel_launch(void* const* d_in, const int* in_sizes, int n_in,
                              void* d_out, int out_size, void* d_ws, size_t ws_size,
                              hipStream_t stream) {
  const float* E = (const float*)d_in[0];
  const int* T = (const int*)d_in[1];
  float* out = (float*)d_out;

  // workspace carve-up (~24.3 MB)
  _Float16* Eh = (_Float16*)d_ws;                     // 4 MB
  _Float16* El = Eh + NROWS * DDIM;                   // 4 MB
  float* sq = (float*)(El + NROWS * DDIM);            // NROWS
  float* pv = sq + NROWS;                             // NROWS*128 (4 MB)
  int*   pi = (int*)(pv + NROWS * NSLOT);             // 4 MB
  float* nv = (float*)(pi + NROWS * NSLOT);           // 4 MB
  int*   ni = (int*)(nv + NROWS * NSLOT);             // 4 MB
  float* bl = (float*)(ni + NROWS * NSLOT);           // NROWS/4

  prep_kernel<<<NROWS / 16, 256, 0, stream>>>(E, Eh, El, sq);
  mine_kernel<<<NTT * NTT, 64, 0, stream>>>(Eh, El, T, sq, pv, pi, nv, ni);
  finish_kernel<<<NROWS / 4, 256, 0, stream>>>(E, pv, pi, nv, ni, out, bl);
  sum_kernel<<<1, 256, 0, stream>>>(bl, out);
}